// Round 4
// baseline (194.484 us; speedup 1.0000x reference)
//
#include <hip/hip_runtime.h>

// DiffKS: x = invert_lpc(y, A_exc)  [order-6 time-varying FIR]
//         out = sample_wise_lpc(x, A_loop)  [order-2 time-varying IIR]
// B=48, T=88200, fp32.
//
// R4 design: one wave per 480-output chunk, 8 samples/lane (window 512).
//  - Per-lane direct global loads, all 16B-aligned float4: y 2, y-halo 2
//    (replaces 8 bpermute shuffles; halo data is L1-hot from neighbors),
//    A_exc 12, A_loop 4.
//  - 32-sample zero-state warm-up (lanes 0..3). ||M_2step||_inf <= 0.5 ->
//    ||P(32)|| <= 1.5e-5: truncation ~1e-4 << 0.11 threshold.
//  - Per-lane affine compose of 8 IIR steps; Hillis-Steele scan truncated
//    to d=1,2 (full 2x2+vec) + d=4 (c-only) + exclusive shfl: 16 bpermutes
//    per 512 samples (R3 had 30 per 256). Output lanes >=4 get exact
//    zero-state coverage (lanes 4..7) or 64-step history (err <= 2e-9).
//  - Direct coalesced float4 stores from registers (lanes 4..63).

#define T_LEN 88200
#define B_N   48
#define OUT_W 480          // output samples per wave
#define WUP   32           // warm-up samples (lanes 0..3)
#define NCH   184          // ceil(T_LEN / OUT_W); 183*480=87840, tail=360
#define WPB   4            // waves per block (block = 256)

__device__ __forceinline__ float4 zero4() { return make_float4(0.f, 0.f, 0.f, 0.f); }

__device__ __forceinline__ float4 ld_g(const float* __restrict__ p, int t) {
    // whole-float4 guard; callers guarantee t % 4 == 0
    if (t >= 0 && t + 3 < T_LEN) return *(const float4*)(p + t);
    return zero4();
}

__global__ __launch_bounds__(256, 4) void diffks_kernel(
    const float* __restrict__ y, const float* __restrict__ A_exc,
    const float* __restrict__ A_loop, float* __restrict__ out) {
    const int tid  = threadIdx.x;
    const int widx = tid >> 6;
    const int lane = tid & 63;
    const int w = blockIdx.x * WPB + widx;      // 0..8831 (grid exact)
    const int b = w / NCH;
    const int c = w - b * NCH;
    const int s  = c * OUT_W;
    const int t0 = s - WUP + 8 * lane;          // lane's first sample (mult of 8)

    const float* yb  = y      + (size_t)b * T_LEN;
    const float* aeb = A_exc  + (size_t)b * T_LEN * 6;
    const float* alb = A_loop + (size_t)b * T_LEN * 2;
    float*       ob  = out    + (size_t)b * T_LEN;

    // ---- per-lane direct loads (T_LEN % 8 == 0, t0 % 8 == 0: whole-lane
    //      slices are either fully in-bounds or fully out) ----
    const bool full = (t0 >= 0) && (t0 < T_LEN);
    float4 ya, yc, ae[12], al[4];
    if (full) {
        const float4* py = (const float4*)(yb + t0);
        ya = py[0]; yc = py[1];
        const float4* pa = (const float4*)(aeb + (size_t)t0 * 6);
#pragma unroll
        for (int i = 0; i < 12; ++i) ae[i] = pa[i];
        const float4* pl = (const float4*)(alb + (size_t)t0 * 2);
#pragma unroll
        for (int i = 0; i < 4; ++i) al[i] = pl[i];
    } else {
        ya = yc = zero4();
#pragma unroll
        for (int i = 0; i < 12; ++i) ae[i] = zero4();
#pragma unroll
        for (int i = 0; i < 4; ++i) al[i] = zero4();
    }
    const float4 hm2 = ld_g(yb, t0 - 8);   // y[t0-8..t0-5]
    const float4 hm1 = ld_g(yb, t0 - 4);   // y[t0-4..t0-1]

    float yw[16] = { hm2.x, hm2.y, hm2.z, hm2.w, hm1.x, hm1.y, hm1.z, hm1.w,
                     ya.x,  ya.y,  ya.z,  ya.w,  yc.x,  yc.y,  yc.z,  yc.w };
    const float* aef = (const float*)ae;   // 48 contiguous floats
    const float* alf = (const float*)al;   // 16 contiguous floats

    // ---- FIR + local affine composition over 8 samples ----
    float xs[8], a1s[8], a2s[8];
    float p00 = 1.f, p01 = 0.f, p10 = 0.f, p11 = 1.f, c0 = 0.f, c1 = 0.f;
#pragma unroll
    for (int j = 0; j < 8; ++j) {
        float xv = yw[8 + j];
#pragma unroll
        for (int k = 1; k <= 6; ++k)
            xv = fmaf(aef[j * 6 + (k - 1)], yw[8 + j - k], xv);
        xs[j] = xv;
        const float a1 = alf[2 * j], a2 = alf[2 * j + 1];
        a1s[j] = a1; a2s[j] = a2;
        // P <- M_t * P ; c <- M_t * c + b_t   (M_t = [[-a1,-a2],[1,0]])
        const float n00 = fmaf(-a1, p00, -a2 * p10);
        const float n01 = fmaf(-a1, p01, -a2 * p11);
        p10 = p00; p11 = p01; p00 = n00; p01 = n01;
        const float nc0 = fmaf(-a1, c0, fmaf(-a2, c1, xv));
        c1 = c0; c0 = nc0;
    }

    // ---- truncated wave scan: d=1,2 full; d=4 c-only ----
#pragma unroll
    for (int d = 1; d <= 2; d <<= 1) {
        const float q00 = __shfl_up(p00, d, 64), q01 = __shfl_up(p01, d, 64);
        const float q10 = __shfl_up(p10, d, 64), q11 = __shfl_up(p11, d, 64);
        const float qc0 = __shfl_up(c0, d, 64),  qc1 = __shfl_up(c1, d, 64);
        if (lane >= d) {
            const float m00 = fmaf(p00, q00, p01 * q10);
            const float m01 = fmaf(p00, q01, p01 * q11);
            const float m10 = fmaf(p10, q00, p11 * q10);
            const float m11 = fmaf(p10, q01, p11 * q11);
            const float nc0 = fmaf(p00, qc0, fmaf(p01, qc1, c0));
            const float nc1 = fmaf(p10, qc0, fmaf(p11, qc1, c1));
            p00 = m00; p01 = m01; p10 = m10; p11 = m11; c0 = nc0; c1 = nc1;
        }
    }
    {   // d = 4: incoming P spans >=32 steps (norm <=1.5e-5) -> c only
        const float qc0 = __shfl_up(c0, 4, 64), qc1 = __shfl_up(c1, 4, 64);
        if (lane >= 4) {
            const float nc0 = fmaf(p00, qc0, fmaf(p01, qc1, c0));
            const float nc1 = fmaf(p10, qc0, fmaf(p11, qc1, c1));
            c0 = nc0; c1 = nc1;
        }
    }

    // ---- exclusive prefix = incoming state; replay 8 samples ----
    float y1 = __shfl_up(c0, 1, 64);
    float y2 = __shfl_up(c1, 1, 64);
    if (lane == 0) { y1 = 0.f; y2 = 0.f; }
    float ov[8];
#pragma unroll
    for (int j = 0; j < 8; ++j) {
        const float yt = fmaf(-a1s[j], y1, fmaf(-a2s[j], y2, xs[j]));
        y2 = y1; y1 = yt;
        ov[j] = yt;
    }

    // ---- direct coalesced stores (lanes 4..63 = output region) ----
    if (lane >= WUP / 8 && t0 < T_LEN) {
        *(float4*)(ob + t0)     = make_float4(ov[0], ov[1], ov[2], ov[3]);
        *(float4*)(ob + t0 + 4) = make_float4(ov[4], ov[5], ov[6], ov[7]);
    }
}

extern "C" void kernel_launch(void* const* d_in, const int* in_sizes, int n_in,
                              void* d_out, int out_size, void* d_ws, size_t ws_size,
                              hipStream_t stream) {
    const float* y      = (const float*)d_in[0];
    const float* A_exc  = (const float*)d_in[1];
    const float* A_loop = (const float*)d_in[2];
    float* out = (float*)d_out;

    const int waves = B_N * NCH;          // 48 * 184 = 8832
    const int grid  = waves / WPB;        // 2208 blocks of 4 waves
    diffks_kernel<<<grid, 256, 0, stream>>>(y, A_exc, A_loop, out);
}